// Round 2
// baseline (197.151 us; speedup 1.0000x reference)
//
#include <hip/hip_runtime.h>
#include <hip/hip_bf16.h>

#define LL 2048
#define NB 8
#define L2E 1.4426950408889634f

typedef float f32x4 __attribute__((ext_vector_type(4)));
typedef short s16x8 __attribute__((ext_vector_type(8)));
typedef unsigned int u32;

__device__ __forceinline__ unsigned short f2bf(float f) {
  u32 u = __float_as_uint(f);
  return (unsigned short)((u + 0x7FFFu + ((u >> 16) & 1u)) >> 16);
}

// ---------------- Projection: q,k,v = W*x + b ----------------
// x: [B][128][L] fp32.  Writes:
//   Qt [B][L][64] bf16 (row i contiguous over f)  -> MFMA A-operand for QK^T
//   Kt [B][L][64] bf16 (row j contiguous over f)  -> MFMA B-operand for QK^T
//   Vf [B][128][L] bf16 (row f contiguous over j) -> MFMA B-operand for PV
__global__ __launch_bounds__(256, 1) void proj_kernel(
    const float* __restrict__ x,
    const float* __restrict__ Wq, const float* __restrict__ bq,
    const float* __restrict__ Wk, const float* __restrict__ bk,
    const float* __restrict__ Wv, const float* __restrict__ bv,
    unsigned short* __restrict__ Qt,
    unsigned short* __restrict__ Kt,
    unsigned short* __restrict__ Vf)
{
  __shared__ float4 Wl[256 * 32];   // 256 out-features x 128 in, fp32 (128 KB)
  __shared__ float  bl[256];

  const int t = threadIdx.x;
  const float4* wq4 = (const float4*)Wq;
  const float4* wk4 = (const float4*)Wk;
  const float4* wv4 = (const float4*)Wv;
  #pragma unroll
  for (int i = 0; i < 8; ++i)  Wl[i * 256 + t]        = wq4[i * 256 + t];
  #pragma unroll
  for (int i = 0; i < 8; ++i)  Wl[2048 + i * 256 + t] = wk4[i * 256 + t];
  #pragma unroll
  for (int i = 0; i < 16; ++i) Wl[4096 + i * 256 + t] = wv4[i * 256 + t];
  bl[t] = (t < 64) ? bq[t] : (t < 128) ? bk[t - 64] : bv[t - 128];
  __syncthreads();

  const int fg = t >> 6;                  // wave: 0=q, 1=k, 2,3=v halves
  const int l  = t & 63;
  const int b  = blockIdx.y;
  const int gl = blockIdx.x * 64 + l;

  float acc[64];
  #pragma unroll
  for (int i = 0; i < 64; ++i) acc[i] = 0.f;

  const float* xb = x + (size_t)b * 128 * LL + gl;

  for (int c0 = 0; c0 < 128; c0 += 4) {
    float x0 = xb[(c0 + 0) * LL];
    float x1 = xb[(c0 + 1) * LL];
    float x2 = xb[(c0 + 2) * LL];
    float x3 = xb[(c0 + 3) * LL];
    #pragma unroll
    for (int ff = 0; ff < 64; ++ff) {
      float4 wv4v = Wl[(fg * 64 + ff) * 32 + (c0 >> 2)];
      acc[ff] = fmaf(x0, wv4v.x, acc[ff]);
      acc[ff] = fmaf(x1, wv4v.y, acc[ff]);
      acc[ff] = fmaf(x2, wv4v.z, acc[ff]);
      acc[ff] = fmaf(x3, wv4v.w, acc[ff]);
    }
  }
  #pragma unroll
  for (int ff = 0; ff < 64; ++ff) acc[ff] += bl[fg * 64 + ff];

  if (fg < 2) {
    unsigned short* dst = (fg == 0 ? Qt : Kt) + ((size_t)b * LL + gl) * 64;
    #pragma unroll
    for (int v = 0; v < 8; ++v) {
      s16x8 pk;
      #pragma unroll
      for (int e = 0; e < 8; ++e) pk[e] = (short)f2bf(acc[v * 8 + e]);
      *(s16x8*)(dst + v * 8) = pk;
    }
  } else {
    unsigned short* dst = Vf + ((size_t)b * 128 + (size_t)(fg - 2) * 64) * LL + gl;
    #pragma unroll
    for (int ff = 0; ff < 64; ++ff) dst[(size_t)ff * LL] = f2bf(acc[ff]);
  }
}

// ---------------- Flash attention + epilogue ----------------
// Per block: batch b, 64 q-rows. 4 waves, each owns 16 rows.
// Per 64-wide j tile: stage K,V in LDS (xor-swizzled 16B chunks), QK^T MFMA,
// online softmax (shfl_xor over 16-lane groups), P via padded LDS, PV MFMA.
// 1-D grid of 256 with bijective XCD chunk swizzle: each XCD's 32 blocks are
// one batch -> that batch's K/V (~1.25 MB) stays resident in the XCD's 4MB L2.
__global__ __launch_bounds__(256, 1) void attn_kernel(
    const unsigned short* __restrict__ Qt,
    const unsigned short* __restrict__ Kt,
    const unsigned short* __restrict__ Vf,
    const float* __restrict__ x,
    const float* __restrict__ gammap,
    float* __restrict__ out)
{
  __shared__ uint4 ldsK4[64 * 8];            // K tile  [j=64][8 chunks] swizzled
  __shared__ uint4 ldsV4[128 * 8];           // V tile  [f=128][8 chunks] swizzled
  __shared__ __align__(16) unsigned short Plds[4][16][80];  // per-wave P, pad->160B rows
  __shared__ float Olds[4][16][129];         // per-wave O transpose, pad +1

  const int t    = threadIdx.x;
  const int w    = t >> 6;
  const int lane = t & 63;
  const int cn   = lane & 15;   // MFMA: A row / B col / D col
  const int g    = lane >> 4;   // MFMA: k-group / D row-group
  // XCD-bijective swizzle (256 blocks % 8 XCDs == 0): round-robin XCD c gets
  // virt ids [c*32, (c+1)*32) == all 32 q-tiles of batch c.
  const int bid  = blockIdx.x;
  const int virt = (bid & 7) * 32 + (bid >> 3);
  const int b    = virt >> 5;
  const int i0   = (virt & 31) * 64;

  // Q fragments (A operand), rows i0 + w*16 + cn, kept in registers
  s16x8 qf[2];
  {
    const unsigned short* qp = Qt + ((size_t)b * LL + i0 + w * 16 + cn) * 64 + g * 8;
    qf[0] = *(const s16x8*)(qp);
    qf[1] = *(const s16x8*)(qp + 32);
  }

  const f32x4 zero4 = {0.f, 0.f, 0.f, 0.f};
  f32x4 accO[8];
  #pragma unroll
  for (int i = 0; i < 8; ++i) accO[i] = zero4;
  float mrow[4], lrow[4];
  #pragma unroll
  for (int r = 0; r < 4; ++r) { mrow[r] = -1e30f; lrow[r] = 0.f; }

  for (int jt = 0; jt < 32; ++jt) {
    const int j0 = jt * 64;
    __syncthreads();   // previous tile fully consumed

    // ---- stage K (512 chunks) and V (1024 chunks), swizzle chunk ^= row&7 ----
    #pragma unroll
    for (int e = 0; e < 2; ++e) {
      int q = e * 256 + t, r = q >> 3, c = q & 7;
      uint4 d = *(const uint4*)(Kt + ((size_t)b * LL + j0 + r) * 64 + c * 8);
      ldsK4[r * 8 + (c ^ (r & 7))] = d;
    }
    #pragma unroll
    for (int e = 0; e < 4; ++e) {
      int q = e * 256 + t, r = q >> 3, c = q & 7;
      uint4 d = *(const uint4*)(Vf + ((size_t)b * 128 + r) * LL + j0 + c * 8);
      ldsV4[r * 8 + (c ^ (r & 7))] = d;
    }
    __syncthreads();   // staged tile visible

    // ---- S = Q^T K  (16i x 64j per wave) ----
    f32x4 s[4];
    #pragma unroll
    for (int jb = 0; jb < 4; ++jb) s[jb] = zero4;
    #pragma unroll
    for (int kt = 0; kt < 2; ++kt) {
      #pragma unroll
      for (int jb = 0; jb < 4; ++jb) {
        int r = jb * 16 + cn;
        s16x8 kf = *(const s16x8*)&ldsK4[r * 8 + ((kt * 4 + g) ^ (cn & 7))];
        s[jb] = __builtin_amdgcn_mfma_f32_16x16x32_bf16(qf[kt], kf, s[jb], 0, 0, 0);
      }
    }

    // ---- online softmax (rows = 4g+r, cols spread over 16 lanes x 4 jb) ----
    float tm[4];
    #pragma unroll
    for (int r = 0; r < 4; ++r) {
      tm[r] = fmaxf(fmaxf(s[0][r], s[1][r]), fmaxf(s[2][r], s[3][r]));
      tm[r] = fmaxf(tm[r], __shfl_xor(tm[r], 1));
      tm[r] = fmaxf(tm[r], __shfl_xor(tm[r], 2));
      tm[r] = fmaxf(tm[r], __shfl_xor(tm[r], 4));
      tm[r] = fmaxf(tm[r], __shfl_xor(tm[r], 8));
    }
    float alpha[4];
    #pragma unroll
    for (int r = 0; r < 4; ++r) {
      float mn = fmaxf(mrow[r], tm[r]);
      alpha[r] = __builtin_amdgcn_exp2f((mrow[r] - mn) * L2E);
      mrow[r] = mn;
    }
    float rs[4] = {0.f, 0.f, 0.f, 0.f};
    float p[4][4];
    #pragma unroll
    for (int jb = 0; jb < 4; ++jb) {
      #pragma unroll
      for (int r = 0; r < 4; ++r) {
        float pv = __builtin_amdgcn_exp2f((s[jb][r] - mrow[r]) * L2E);
        p[jb][r] = pv;
        rs[r] += pv;
      }
    }
    #pragma unroll
    for (int r = 0; r < 4; ++r) {
      rs[r] += __shfl_xor(rs[r], 1);
      rs[r] += __shfl_xor(rs[r], 2);
      rs[r] += __shfl_xor(rs[r], 4);
      rs[r] += __shfl_xor(rs[r], 8);
      lrow[r] = lrow[r] * alpha[r] + rs[r];
    }
    #pragma unroll
    for (int fb = 0; fb < 8; ++fb) {
      #pragma unroll
      for (int r = 0; r < 4; ++r) accO[fb][r] *= alpha[r];
    }

    // ---- P -> LDS (bf16, S-layout in, A-layout out) ----
    #pragma unroll
    for (int jb = 0; jb < 4; ++jb) {
      #pragma unroll
      for (int r = 0; r < 4; ++r)
        Plds[w][g * 4 + r][jb * 16 + cn] = f2bf(p[jb][r]);
    }

    // ---- O += P V^T ----
    #pragma unroll
    for (int kt = 0; kt < 2; ++kt) {
      s16x8 pa = *(const s16x8*)((const unsigned short*)&Plds[w][cn][0] + kt * 32 + g * 8);
      #pragma unroll
      for (int fb = 0; fb < 8; ++fb) {
        int f = fb * 16 + cn;
        s16x8 vf = *(const s16x8*)&ldsV4[f * 8 + ((kt * 4 + g) ^ (cn & 7))];
        accO[fb] = __builtin_amdgcn_mfma_f32_16x16x32_bf16(pa, vf, accO[fb], 0, 0, 0);
      }
    }
  }

  // ---- epilogue: O/l -> LDS transpose -> out = gamma*O + x (coalesced) ----
  #pragma unroll
  for (int r = 0; r < 4; ++r) {
    float inv = 1.f / lrow[r];
    #pragma unroll
    for (int fb = 0; fb < 8; ++fb)
      Olds[w][g * 4 + r][fb * 16 + cn] = accO[fb][r] * inv;
  }
  __syncthreads();
  const float gamma = gammap[0];
  {
    const int r = cn;
    const int row = i0 + w * 16 + r;
    #pragma unroll
    for (int ff = 0; ff < 32; ++ff) {
      int f = ff * 4 + g;
      float val = Olds[w][r][f];
      size_t idx = ((size_t)b * 128 + f) * LL + row;
      out[idx] = gamma * val + x[idx];
    }
  }
}

extern "C" void kernel_launch(void* const* d_in, const int* in_sizes, int n_in,
                              void* d_out, int out_size, void* d_ws, size_t ws_size,
                              hipStream_t stream) {
  const float* x     = (const float*)d_in[0];
  const float* Wq    = (const float*)d_in[1];
  const float* bq    = (const float*)d_in[2];
  const float* Wk    = (const float*)d_in[3];
  const float* bk    = (const float*)d_in[4];
  const float* Wv    = (const float*)d_in[5];
  const float* bv    = (const float*)d_in[6];
  const float* gamma = (const float*)d_in[7];
  float* out = (float*)d_out;

  // workspace: Qt 2MB | Kt 2MB | Vf 4MB   (bf16)
  unsigned short* Qt = (unsigned short*)d_ws;
  unsigned short* Kt = Qt + (size_t)NB * LL * 64;
  unsigned short* Vf = Kt + (size_t)NB * LL * 64;

  proj_kernel<<<dim3(32, 8), 256, 0, stream>>>(x, Wq, bq, Wk, bk, Wv, bv, Qt, Kt, Vf);
  attn_kernel<<<dim3(256), 256, 0, stream>>>(Qt, Kt, Vf, x, gamma, out);
}

// Round 11
// 167.946 us; speedup vs baseline: 1.1739x; 1.1739x over previous
//
#include <hip/hip_runtime.h>
#include <hip/hip_bf16.h>

#define LL 2048
#define NB 8
#define L2E 1.4426950408889634f

typedef float f32x4 __attribute__((ext_vector_type(4)));
typedef short s16x8 __attribute__((ext_vector_type(8)));
typedef unsigned int u32;
typedef unsigned int u32x2 __attribute__((ext_vector_type(2)));
typedef unsigned int u32x4 __attribute__((ext_vector_type(4)));

__device__ __forceinline__ unsigned short f2bf(float f) {
  u32 u = __float_as_uint(f);
  return (unsigned short)((u + 0x7FFFu + ((u >> 16) & 1u)) >> 16);
}
__device__ __forceinline__ u32 pack2(float a, float b) {
  return (u32)f2bf(a) | ((u32)f2bf(b) << 16);
}

// ---------------- Projection (MFMA): q,k,v = W*x + b ----------------
// GEMM: [256 f][128 c] x [128 c][16384 l].  Per block: one batch, 64 cols.
// Wave w owns f in [w*64, w*64+64).  A-frags (W rows) straight from global
// (W is 128KB -> L2-resident); x transposed to swizzled LDS tile.
// Outputs: Qt/Kt [B][L][64] bf16, Vf [B][128][L] bf16.
__global__ __launch_bounds__(256, 1) void proj_kernel(
    const float* __restrict__ x,
    const float* __restrict__ Wq, const float* __restrict__ bq,
    const float* __restrict__ Wk, const float* __restrict__ bk,
    const float* __restrict__ Wv, const float* __restrict__ bv,
    unsigned short* __restrict__ Qt,
    unsigned short* __restrict__ Kt,
    unsigned short* __restrict__ Vf)
{
  __shared__ __align__(16) unsigned short xT[64 * 128];  // [l 64][c 128] bf16, 16B-chunk swizzled
  __shared__ float bl[256];

  const int t  = threadIdx.x;
  const int w  = t >> 6;       // wave
  const int ll = t & 63;
  const int lane = t & 63;
  const int cn = lane & 15;
  const int g  = lane >> 4;
  const int b  = blockIdx.x >> 5;
  const int l0 = (blockIdx.x & 31) * 64;

  // ---- A-fragments: W rows f0+fb*16+cn, k-chunk kt*32+g*8, bf16-converted ----
  const int f0 = w * 64;
  s16x8 afr[4][4];
  #pragma unroll
  for (int fb = 0; fb < 4; ++fb) {
    const int f = f0 + fb * 16 + cn;
    const float* p = (f < 64) ? (Wq + (size_t)f * 128)
                   : (f < 128) ? (Wk + (size_t)(f - 64) * 128)
                               : (Wv + (size_t)(f - 128) * 128);
    #pragma unroll
    for (int kt = 0; kt < 4; ++kt) {
      const float4 u = *(const float4*)(p + kt * 32 + g * 8);
      const float4 v = *(const float4*)(p + kt * 32 + g * 8 + 4);
      u32x4 pk = {pack2(u.x, u.y), pack2(u.z, u.w), pack2(v.x, v.y), pack2(v.z, v.w)};
      afr[fb][kt] = __builtin_bit_cast(s16x8, pk);
    }
  }

  // ---- stage x^T tile: [64 l][c 128] bf16, chunk' = (c/8) ^ (l&15) ----
  {
    const float* xb = x + (size_t)b * 128 * LL + l0 + ll;
    #pragma unroll
    for (int it = 0; it < 4; ++it) {
      const int ch = it * 4 + w;          // chunk = c/8 in 0..15
      const float* p = xb + (size_t)ch * 8 * LL;
      float v[8];
      #pragma unroll
      for (int j = 0; j < 8; ++j) v[j] = p[(size_t)j * LL];
      u32x4 pk = {pack2(v[0], v[1]), pack2(v[2], v[3]),
                  pack2(v[4], v[5]), pack2(v[6], v[7])};
      *(u32x4*)&xT[ll * 128 + ((ch ^ (ll & 15)) * 8)] = pk;
    }
  }
  bl[t] = (t < 64) ? bq[t] : (t < 128) ? bk[t - 64] : bv[t - 128];
  __syncthreads();

  // ---- MFMA: acc[fb][lb] = W-tile x xT-tile ----
  const f32x4 zero4 = {0.f, 0.f, 0.f, 0.f};
  f32x4 acc[4][4];
  #pragma unroll
  for (int fb = 0; fb < 4; ++fb)
    #pragma unroll
    for (int lb = 0; lb < 4; ++lb) acc[fb][lb] = zero4;

  #pragma unroll
  for (int kt = 0; kt < 4; ++kt) {
    s16x8 bfr[4];
    #pragma unroll
    for (int lb = 0; lb < 4; ++lb)
      bfr[lb] = *(const s16x8*)&xT[(lb * 16 + cn) * 128 + (((kt * 4 + g) ^ cn) * 8)];
    #pragma unroll
    for (int fb = 0; fb < 4; ++fb)
      #pragma unroll
      for (int lb = 0; lb < 4; ++lb)
        acc[fb][lb] = __builtin_amdgcn_mfma_f32_16x16x32_bf16(afr[fb][kt], bfr[lb], acc[fb][lb], 0, 0, 0);
  }

  // ---- + bias;  D: row f = f0+fb*16+4g+r, col l = l0+lb*16+cn ----
  #pragma unroll
  for (int fb = 0; fb < 4; ++fb) {
    float bb0 = bl[f0 + fb * 16 + 4 * g + 0];
    float bb1 = bl[f0 + fb * 16 + 4 * g + 1];
    float bb2 = bl[f0 + fb * 16 + 4 * g + 2];
    float bb3 = bl[f0 + fb * 16 + 4 * g + 3];
    #pragma unroll
    for (int lb = 0; lb < 4; ++lb) {
      acc[fb][lb][0] += bb0; acc[fb][lb][1] += bb1;
      acc[fb][lb][2] += bb2; acc[fb][lb][3] += bb3;
    }
  }

  if (w < 2) {
    // Qt/Kt [b][l][64]: pack 4 contiguous f (r=0..3) into one 8B store
    unsigned short* base = (w == 0 ? Qt : Kt) + (size_t)b * LL * 64;
    #pragma unroll
    for (int lb = 0; lb < 4; ++lb) {
      const int l = l0 + lb * 16 + cn;
      #pragma unroll
      for (int fb = 0; fb < 4; ++fb) {
        u32x2 pk = {pack2(acc[fb][lb][0], acc[fb][lb][1]),
                    pack2(acc[fb][lb][2], acc[fb][lb][3])};
        *(u32x2*)(base + (size_t)l * 64 + fb * 16 + 4 * g) = pk;
      }
    }
  } else {
    // Vf [b][f][l]: scalar bf16 stores (16-lane 32B segments)
    unsigned short* base = Vf + ((size_t)b * 128 + (size_t)(w - 2) * 64) * LL;
    #pragma unroll
    for (int fb = 0; fb < 4; ++fb)
      #pragma unroll
      for (int lb = 0; lb < 4; ++lb) {
        const int l = l0 + lb * 16 + cn;
        #pragma unroll
        for (int r = 0; r < 4; ++r)
          base[(size_t)(fb * 16 + 4 * g + r) * LL + l] = f2bf(acc[fb][lb][r]);
      }
  }
}

// ---------------- Flash attention + epilogue ----------------
// Per block: batch b, 64 q-rows. 4 waves, each owns 16 rows.
// Pipeline per 64-wide j tile (ONE barrier per tile):
//   barrier -> issue next tile's global loads to regs -> QK^T/softmax/PV on
//   current LDS buffer -> vmcnt-wait -> swizzled ds_write to alternate buffer.
// Safety: reads of buf X in iter t finish before barrier(t+1); writes to X
// happen only after barrier(t+1).  Double-buffered K/V = 2 x 24 KB.
// 1-D grid of 256 with bijective XCD chunk swizzle: each XCD's 32 blocks are
// one batch -> that batch's K/V (~1.25 MB) stays resident in the XCD's 4MB L2.
// Plds row stride 72 ushorts = 144 B = 36 banks: PV b128 read -> exact 2-way
// bank aliasing (free, m136); 80 (160 B) was a 4-way read / 8-way write.
__global__ __launch_bounds__(256, 1) void attn_kernel(
    const unsigned short* __restrict__ Qt,
    const unsigned short* __restrict__ Kt,
    const unsigned short* __restrict__ Vf,
    const float* __restrict__ x,
    const float* __restrict__ gammap,
    float* __restrict__ out)
{
  __shared__ uint4 ldsK4[2][64 * 8];         // K tiles [j=64][8 chunks] swizzled
  __shared__ uint4 ldsV4[2][128 * 8];        // V tiles [f=128][8 chunks] swizzled
  __shared__ __align__(16) unsigned short Plds[4][16][72];  // per-wave P, 144B rows
  __shared__ float Olds[4][16][129];         // per-wave O transpose, pad +1

  const int t    = threadIdx.x;
  const int w    = t >> 6;
  const int lane = t & 63;
  const int cn   = lane & 15;   // MFMA: A row / B col / D col
  const int g    = lane >> 4;   // MFMA: k-group / D row-group
  const int bid  = blockIdx.x;
  const int virt = (bid & 7) * 32 + (bid >> 3);
  const int b    = virt >> 5;
  const int i0   = (virt & 31) * 64;

  // Q fragments (A operand), rows i0 + w*16 + cn, kept in registers
  s16x8 qf[2];
  {
    const unsigned short* qp = Qt + ((size_t)b * LL + i0 + w * 16 + cn) * 64 + g * 8;
    qf[0] = *(const s16x8*)(qp);
    qf[1] = *(const s16x8*)(qp + 32);
  }

  // staging registers for one K/V tile (6 x 16B per thread)
  uint4 kreg[2], vreg[4];
  const int sr_k[2] = { t >> 3, (256 + t) >> 3 };
  const int sc     = t & 7;
  const int sr_v[4] = { t >> 3, (256 + t) >> 3, (512 + t) >> 3, (768 + t) >> 3 };

  auto issue_loads = [&](int j0) {
    #pragma unroll
    for (int e = 0; e < 2; ++e)
      kreg[e] = *(const uint4*)(Kt + ((size_t)b * LL + j0 + sr_k[e]) * 64 + sc * 8);
    #pragma unroll
    for (int e = 0; e < 4; ++e)
      vreg[e] = *(const uint4*)(Vf + ((size_t)b * 128 + sr_v[e]) * LL + j0 + sc * 8);
  };
  auto write_lds = [&](uint4* K4, uint4* V4) {
    #pragma unroll
    for (int e = 0; e < 2; ++e)
      K4[sr_k[e] * 8 + (sc ^ (sr_k[e] & 7))] = kreg[e];
    #pragma unroll
    for (int e = 0; e < 4; ++e)
      V4[sr_v[e] * 8 + (sc ^ (sr_v[e] & 7))] = vreg[e];
  };

  const f32x4 zero4 = {0.f, 0.f, 0.f, 0.f};
  f32x4 accO[8];
  #pragma unroll
  for (int i = 0; i < 8; ++i) accO[i] = zero4;
  float mrow[4], lrow[4];
  #pragma unroll
  for (int r = 0; r < 4; ++r) { mrow[r] = -1e30f; lrow[r] = 0.f; }

  // prologue: stage tile 0 into buffer 0
  issue_loads(0);
  write_lds(ldsK4[0], ldsV4[0]);

  for (int jt = 0; jt < 32; ++jt) {
    const int cur = jt & 1;
    __syncthreads();   // buf[cur] writes visible; buf[cur^1] readers all done

    if (jt + 1 < 32) issue_loads((jt + 1) * 64);

    const uint4* K4 = ldsK4[cur];
    const uint4* V4 = ldsV4[cur];

    // ---- S = Q^T K  (16i x 64j per wave) ----
    f32x4 s[4];
    #pragma unroll
    for (int jb = 0; jb < 4; ++jb) s[jb] = zero4;
    #pragma unroll
    for (int kt = 0; kt < 2; ++kt) {
      #pragma unroll
      for (int jb = 0; jb < 4; ++jb) {
        int r = jb * 16 + cn;
        s16x8 kf = *(const s16x8*)&K4[r * 8 + ((kt * 4 + g) ^ (r & 7))];
        s[jb] = __builtin_amdgcn_mfma_f32_16x16x32_bf16(qf[kt], kf, s[jb], 0, 0, 0);
      }
    }

    // ---- online softmax (rows = 4g+r, cols spread over 16 lanes x 4 jb) ----
    float tm[4];
    #pragma unroll
    for (int r = 0; r < 4; ++r) {
      tm[r] = fmaxf(fmaxf(s[0][r], s[1][r]), fmaxf(s[2][r], s[3][r]));
      tm[r] = fmaxf(tm[r], __shfl_xor(tm[r], 1));
      tm[r] = fmaxf(tm[r], __shfl_xor(tm[r], 2));
      tm[r] = fmaxf(tm[r], __shfl_xor(tm[r], 4));
      tm[r] = fmaxf(tm[r], __shfl_xor(tm[r], 8));
    }
    float alpha[4];
    #pragma unroll
    for (int r = 0; r < 4; ++r) {
      float mn = fmaxf(mrow[r], tm[r]);
      alpha[r] = __builtin_amdgcn_exp2f((mrow[r] - mn) * L2E);
      mrow[r] = mn;
    }
    float rs[4] = {0.f, 0.f, 0.f, 0.f};
    float p[4][4];
    #pragma unroll
    for (int jb = 0; jb < 4; ++jb) {
      #pragma unroll
      for (int r = 0; r < 4; ++r) {
        float pv = __builtin_amdgcn_exp2f((s[jb][r] - mrow[r]) * L2E);
        p[jb][r] = pv;
        rs[r] += pv;
      }
    }
    #pragma unroll
    for (int r = 0; r < 4; ++r) {
      rs[r] += __shfl_xor(rs[r], 1);
      rs[r] += __shfl_xor(rs[r], 2);
      rs[r] += __shfl_xor(rs[r], 4);
      rs[r] += __shfl_xor(rs[r], 8);
      lrow[r] = lrow[r] * alpha[r] + rs[r];
    }
    #pragma unroll
    for (int fb = 0; fb < 8; ++fb) {
      #pragma unroll
      for (int r = 0; r < 4; ++r) accO[fb][r] *= alpha[r];
    }

    // ---- P -> LDS (bf16, S-layout in, A-layout out); per-wave region ----
    #pragma unroll
    for (int jb = 0; jb < 4; ++jb) {
      #pragma unroll
      for (int r = 0; r < 4; ++r)
        Plds[w][g * 4 + r][jb * 16 + cn] = f2bf(p[jb][r]);
    }

    // ---- O += P V^T ----
    #pragma unroll
    for (int kt = 0; kt < 2; ++kt) {
      s16x8 pa = *(const s16x8*)((const unsigned short*)&Plds[w][cn][0] + kt * 32 + g * 8);
      #pragma unroll
      for (int fb = 0; fb < 8; ++fb) {
        int f = fb * 16 + cn;
        s16x8 vf = *(const s16x8*)&V4[f * 8 + ((kt * 4 + g) ^ (f & 7))];
        accO[fb] = __builtin_amdgcn_mfma_f32_16x16x32_bf16(pa, vf, accO[fb], 0, 0, 0);
      }
    }

    // ---- write next tile into alternate buffer (after this tile's reads) ----
    if (jt + 1 < 32) write_lds(ldsK4[cur ^ 1], ldsV4[cur ^ 1]);
  }

  // ---- epilogue: O/l -> LDS transpose -> out = gamma*O + x (coalesced) ----
  #pragma unroll
  for (int r = 0; r < 4; ++r) {
    float inv = 1.f / lrow[r];
    #pragma unroll
    for (int fb = 0; fb < 8; ++fb)
      Olds[w][g * 4 + r][fb * 16 + cn] = accO[fb][r] * inv;
  }
  __syncthreads();
  const float gamma = gammap[0];
  {
    const int r = cn;
    const int row = i0 + w * 16 + r;
    #pragma unroll
    for (int ff = 0; ff < 32; ++ff) {
      int f = ff * 4 + g;
      float val = Olds[w][r][f];
      size_t idx = ((size_t)b * 128 + f) * LL + row;
      out[idx] = gamma * val + x[idx];
    }
  }
}

extern "C" void kernel_launch(void* const* d_in, const int* in_sizes, int n_in,
                              void* d_out, int out_size, void* d_ws, size_t ws_size,
                              hipStream_t stream) {
  const float* x     = (const float*)d_in[0];
  const float* Wq    = (const float*)d_in[1];
  const float* bq    = (const float*)d_in[2];
  const float* Wk    = (const float*)d_in[3];
  const float* bk    = (const float*)d_in[4];
  const float* Wv    = (const float*)d_in[5];
  const float* bv    = (const float*)d_in[6];
  const float* gamma = (const float*)d_in[7];
  float* out = (float*)d_out;

  // workspace: Qt 2MB | Kt 2MB | Vf 4MB   (bf16)
  unsigned short* Qt = (unsigned short*)d_ws;
  unsigned short* Kt = Qt + (size_t)NB * LL * 64;
  unsigned short* Vf = Kt + (size_t)NB * LL * 64;

  proj_kernel<<<dim3(256), 256, 0, stream>>>(x, Wq, bq, Wk, bk, Wv, bv, Qt, Kt, Vf);
  attn_kernel<<<dim3(256), 256, 0, stream>>>(Qt, Kt, Vf, x, gamma, out);
}